// Round 3
// baseline (302.958 us; speedup 1.0000x reference)
//
#include <hip/hip_runtime.h>
#include <math.h>

typedef _Float16 f16;
typedef f16 f16x8 __attribute__((ext_vector_type(8)));
typedef float f32x4 __attribute__((ext_vector_type(4)));

#define Bsz   16384
#define Tobs  8
#define PREDL 12
#define MR    32   // batch rows per main block

__device__ __forceinline__ float fast_sigm(float x) {
  float e = __builtin_amdgcn_exp2f(-1.44269504f * x);
  return __builtin_amdgcn_rcpf(1.f + e);
}
__device__ __forceinline__ float fast_tanh(float x) {
  float e = __builtin_amdgcn_exp2f(2.88539008f * x);  // e^(2x)
  return 1.f - 2.f * __builtin_amdgcn_rcpf(1.f + e);
}

// Abuf index helper: [buf(2)][kt(4)][mt(2)][lane(64)][j(8)] f16
#define AB(buf, kt, mt, lane, j) (((((buf)*4 + (kt))*2 + (mt))*64 + (lane))*8 + (j))

// ---------------------------------------------------------------------------
// Wsp_t[c][m] = sum_e W_sp[m][e] * table[c][e]   (c in 0..15, m in 0..127)
// ---------------------------------------------------------------------------
__global__ void wsp_t_kernel(const float* __restrict__ W_sp, const float* __restrict__ table,
                             float* __restrict__ Wsp_t) {
  int gid = blockIdx.x * 256 + threadIdx.x;
  if (gid >= 16 * 128) return;
  int c = gid >> 7, m = gid & 127;
  float s = 0.f;
  for (int e = 0; e < 32; ++e) s += W_sp[m * 32 + e] * table[c * 32 + e];
  Wsp_t[c * 128 + m] = s;
}

// ---------------------------------------------------------------------------
// Wfrag [kt(5)][w(8)][nt(4)][lane(64)][j(8)] fp16. Column perm: j_orig = nt*128 + w*16 + l.
// kt<4: W_hh[k];  kt==4 = extras tile, k'=k-128:
//   k'<16 : W_cell[j][k'] = sum_m W_ih[j][128+m] * Wsp_t[k'][m]
//   k'=16/17: W_io[j][k'-16] = sum_m W_ih[j][m] * W_in[m][k'-16]
//   k'>=18: 0
// ---------------------------------------------------------------------------
__global__ void pack_w_kernel(const float* __restrict__ W_ih, const float* __restrict__ W_hh,
                              const float* __restrict__ W_in, const float* __restrict__ Wsp_t,
                              f16* __restrict__ Wfrag) {
  int gid = blockIdx.x * 256 + threadIdx.x;
  if (gid >= 5 * 8 * 4 * 64 * 8) return;
  int j  = gid & 7;
  int ln = (gid >> 3) & 63;
  int nt = (gid >> 9) & 3;
  int w  = (gid >> 11) & 7;
  int kt = gid >> 14;
  int l = ln & 15, q = ln >> 4;
  int k = kt * 32 + q * 8 + j;
  int jo = nt * 128 + w * 16 + l;
  float v = 0.f;
  if (kt < 4) {
    v = W_hh[jo * 128 + k];
  } else {
    int kk = k - 128;  // 0..31
    if (kk < 16) {
      float s = 0.f;
      for (int m = 0; m < 128; ++m) s += W_ih[jo * 256 + 128 + m] * Wsp_t[kk * 128 + m];
      v = s;
    } else if (kk < 18) {
      int c = kk - 16;
      float s = 0.f;
      for (int m = 0; m < 128; ++m) s += W_ih[jo * 256 + m] * W_in[m * 2 + c];
      v = s;
    }
  }
  Wfrag[gid] = (f16)v;
}

// biasO/biasP (permuted, 512 each) + wio (512x2): biasO folds b_in and b_sp terms.
__global__ void pack_misc_kernel(const float* __restrict__ W_ih, const float* __restrict__ W_in,
                                 const float* __restrict__ b_in, const float* __restrict__ b_sp,
                                 const float* __restrict__ b_ih, const float* __restrict__ b_hh,
                                 float* __restrict__ biasO, float* __restrict__ biasP,
                                 float* __restrict__ wio) {
  int gid = blockIdx.x * 256 + threadIdx.x;
  if (gid >= 2048) return;
  if (gid < 1024) {
    int n = gid & 511;
    int w = n >> 6, nt = (n >> 4) & 3, l = n & 15;
    int jo = nt * 128 + w * 16 + l;
    float s = b_ih[jo] + b_hh[jo];
    for (int m = 0; m < 128; ++m) s += W_ih[jo * 256 + m] * b_in[m];
    if (gid < 512) {
      for (int m = 0; m < 128; ++m) s += W_ih[jo * 256 + 128 + m] * b_sp[m];
      biasO[n] = s;
    } else {
      biasP[n] = s;
    }
  } else {
    int idx = gid - 1024;
    int n = idx >> 1, c = idx & 1;
    int w = n >> 6, nt = (n >> 4) & 3, l = n & 15;
    int jo = nt * 128 + w * 16 + l;
    float s = 0.f;
    for (int m = 0; m < 128; ++m) s += W_ih[jo * 256 + m] * W_in[m * 2 + c];
    wio[n * 2 + c] = s;
  }
}

// ---------------------------------------------------------------------------
// Pool: one WAVE per batch element b; lane = neighbor n. Counts per grid cell
// via ballot+popcount; writes cntx[b][t][32] = [cnt(16) f16 | obs xy (2) | untouched].
// ---------------------------------------------------------------------------
__global__ __launch_bounds__(256) void pool_kernel(const float* __restrict__ obs,
                                                   const float* __restrict__ nb,
                                                   f16* __restrict__ cntx) {
  int tid = threadIdx.x;
  int wv = tid >> 6, ln = tid & 63;
  int b = blockIdx.x * 4 + wv;
  // lane's neighbor track: 8 t * float2 = 64B contiguous
  const float4* nb4 = (const float4*)(nb + (((size_t)b * 64 + ln) * 8) * 2);
  float4 n0 = nb4[0], n1 = nb4[1], n2 = nb4[2], n3 = nb4[3];
  // obs (wave-uniform)
  const float4* ob4 = (const float4*)(obs + (size_t)b * 16);
  float4 o0 = ob4[0], o1 = ob4[1], o2 = ob4[2], o3 = ob4[3];
  float nxv[8] = {n0.x, n0.z, n1.x, n1.z, n2.x, n2.z, n3.x, n3.z};
  float nyv[8] = {n0.y, n0.w, n1.y, n1.w, n2.y, n2.w, n3.y, n3.w};
  float oxv[8] = {o0.x, o0.z, o1.x, o1.z, o2.x, o2.z, o3.x, o3.z};
  float oyv[8] = {o0.y, o0.w, o1.y, o1.w, o2.y, o2.w, o3.y, o3.w};
  int flat[8];
#pragma unroll
  for (int t = 0; t < 8; ++t) {
    float rx = nxv[t] - oxv[t], ry = nyv[t] - oyv[t];
    int ix = (int)floorf(rx + rx);
    int iy = (int)floorf(ry + ry);
    ix = min(max(ix, -2), 1);
    iy = min(max(iy, -2), 1);
    flat[t] = (ix + 2) * 4 + (iy + 2);
  }
  int cnt0 = 0, cnt1 = 0;  // this lane owns (t=ln>>4, c=ln&15) and (t+4, c)
#pragma unroll
  for (int t = 0; t < 8; ++t) {
#pragma unroll
    for (int c = 0; c < 16; ++c) {
      int n = (int)__popcll(__ballot(flat[t] == c));
      if (t < 4) cnt0 = (ln == t * 16 + c) ? n : cnt0;
      else       cnt1 = (ln == (t - 4) * 16 + c) ? n : cnt1;
    }
  }
  int myT = ln >> 4, myC = ln & 15;
  size_t base = (size_t)b * 8;
  cntx[(base + myT) * 32 + myC] = (f16)cnt0;
  cntx[(base + myT + 4) * 32 + myC] = (f16)cnt1;
  if (ln < 8) {  // xy channels 16,17 for t=ln
    float ox2 = obs[base * 2 + ln * 2], oy2 = obs[base * 2 + ln * 2 + 1];
    cntx[(base + ln) * 32 + 16] = (f16)ox2;
    cntx[(base + ln) * 32 + 17] = (f16)oy2;
  }
}

// ---------------------------------------------------------------------------
// Main: 32 batch rows/block, 512 threads (8 waves), 512 blocks (2/CU).
// W_hh fragments persistent in VGPRs; extras tile (cnt|xy) via MFMA in obs;
// pred keeps rank-2 xy update in VALU.
// ---------------------------------------------------------------------------
__global__ __launch_bounds__(512, 4) void social_lstm_main(
    const f16* __restrict__ Wfrag, const float* __restrict__ biasO,
    const float* __restrict__ biasP, const float* __restrict__ wio,
    const f16* __restrict__ cntx, const float* __restrict__ W_out,
    const float* __restrict__ b_out, float* __restrict__ out) {
  __shared__ __align__(16) f16 Abuf[2 * 4 * 2 * 64 * 8];  // 16 KB
  __shared__ float xybuf[2][MR][2];
  __shared__ float red[2][MR][8];

  const int tid = threadIdx.x;
  const int w = tid >> 6, ln = tid & 63;
  const int q = ln >> 4, l = ln & 15;
  const int b0 = blockIdx.x * MR;

  for (int i = tid; i < 2048; i += 512) ((uint32_t*)Abuf)[i] = 0u;  // zero buf 0
  if (tid < 64) xybuf[0][tid >> 1][tid & 1] = 0.f;

  // persistent W_hh B fragments (64 VGPRs)
  f16x8 Bh[4][4];
#pragma unroll
  for (int kt = 0; kt < 4; ++kt)
#pragma unroll
    for (int nt = 0; nt < 4; ++nt)
      Bh[kt][nt] = *(const f16x8*)(Wfrag + (size_t)((((kt * 8 + w) * 4 + nt) * 64 + ln) * 8));

  float creg[8];
#pragma unroll
  for (int i = 0; i < 8; ++i) creg[i] = 0.f;

  float bOr[4];
#pragma unroll
  for (int g = 0; g < 4; ++g) bOr[g] = biasO[w * 64 + g * 16 + l];
  float bPr[4] = {0, 0, 0, 0}, wxr[4] = {0, 0, 0, 0}, wyr[4] = {0, 0, 0, 0};

  const int hc = w * 16 + l;
  const int aw_kt = hc >> 5, aw_quad = (hc >> 3) & 3, aw_j = l & 7;

  f32x4 acc[2][4];

  auto epilogue = [&](const float* bq, bool usexy, int rbuf, int wbuf) {
#pragma unroll
    for (int mt = 0; mt < 2; ++mt) {
#pragma unroll
      for (int reg = 0; reg < 4; ++reg) {
        int m = mt * 16 + q * 4 + reg;
        float p0 = acc[mt][0][reg] + bq[0];
        float p1 = acc[mt][1][reg] + bq[1];
        float p2 = acc[mt][2][reg] + bq[2];
        float p3 = acc[mt][3][reg] + bq[3];
        if (usexy) {
          float px = xybuf[rbuf][m][0], py = xybuf[rbuf][m][1];
          p0 += wxr[0] * px + wyr[0] * py;
          p1 += wxr[1] * px + wyr[1] * py;
          p2 += wxr[2] * px + wyr[2] * py;
          p3 += wxr[3] * px + wyr[3] * py;
        }
        float iv = fast_sigm(p0), fv = fast_sigm(p1);
        float gv = fast_tanh(p2), ov = fast_sigm(p3);
        int ci = mt * 4 + reg;
        float c2 = fv * creg[ci] + iv * gv;
        creg[ci] = c2;
        float hv = ov * fast_tanh(c2);
        Abuf[AB(wbuf, aw_kt, mt, (q * 4 + reg) + 16 * aw_quad, aw_j)] = (f16)hv;
      }
    }
  };

  // ---------------- observation phase: 1 barrier per step ----------------
#pragma unroll
  for (int t = 0; t < Tobs; ++t) {
    const int rb = t & 1, wb = rb ^ 1;
    __syncthreads();
    // extras fragments: A from cntx (global), B = Wfrag kt=4
    f16x8 Ax[2], Bx[4];
#pragma unroll
    for (int mt = 0; mt < 2; ++mt)
      Ax[mt] = *(const f16x8*)(cntx + ((size_t)(b0 + mt * 16 + l) * Tobs + t) * 32 + q * 8);
#pragma unroll
    for (int nt = 0; nt < 4; ++nt)
      Bx[nt] = *(const f16x8*)(Wfrag + (size_t)((((4 * 8 + w) * 4 + nt) * 64 + ln) * 8));
#pragma unroll
    for (int mt = 0; mt < 2; ++mt)
#pragma unroll
      for (int nt = 0; nt < 4; ++nt) acc[mt][nt] = (f32x4){0.f, 0.f, 0.f, 0.f};
#pragma unroll
    for (int kt = 0; kt < 2; ++kt) {
      f16x8 Af[2];
#pragma unroll
      for (int mt = 0; mt < 2; ++mt) Af[mt] = *(const f16x8*)(&Abuf[AB(rb, kt, mt, ln, 0)]);
#pragma unroll
      for (int mt = 0; mt < 2; ++mt)
#pragma unroll
        for (int nt = 0; nt < 4; ++nt)
          acc[mt][nt] = __builtin_amdgcn_mfma_f32_16x16x32_f16(Af[mt], Bh[kt][nt], acc[mt][nt], 0, 0, 0);
    }
#pragma unroll
    for (int mt = 0; mt < 2; ++mt)
#pragma unroll
      for (int nt = 0; nt < 4; ++nt)
        acc[mt][nt] = __builtin_amdgcn_mfma_f32_16x16x32_f16(Ax[mt], Bx[nt], acc[mt][nt], 0, 0, 0);
#pragma unroll
    for (int kt = 2; kt < 4; ++kt) {
      f16x8 Af[2];
#pragma unroll
      for (int mt = 0; mt < 2; ++mt) Af[mt] = *(const f16x8*)(&Abuf[AB(rb, kt, mt, ln, 0)]);
#pragma unroll
      for (int mt = 0; mt < 2; ++mt)
#pragma unroll
        for (int nt = 0; nt < 4; ++nt)
          acc[mt][nt] = __builtin_amdgcn_mfma_f32_16x16x32_f16(Af[mt], Bh[kt][nt], acc[mt][nt], 0, 0, 0);
    }
    epilogue(bOr, false, rb, wb);
  }

  // pred-phase constants
#pragma unroll
  for (int g = 0; g < 4; ++g) {
    int col = w * 64 + g * 16 + l;
    bPr[g] = biasP[col];
    wxr[g] = wio[col * 2];
    wyr[g] = wio[col * 2 + 1];
  }

  // ---------------- prediction phase ----------------
  for (int p = 0; p < PREDL; ++p) {
    const int s = Tobs + p;
    const int rb = s & 1, wb = rb ^ 1;
    __syncthreads();  // barrier A
#pragma unroll
    for (int mt = 0; mt < 2; ++mt)
#pragma unroll
      for (int nt = 0; nt < 4; ++nt) acc[mt][nt] = (f32x4){0.f, 0.f, 0.f, 0.f};
#pragma unroll
    for (int kt = 0; kt < 4; ++kt) {
      f16x8 Af[2];
#pragma unroll
      for (int mt = 0; mt < 2; ++mt) Af[mt] = *(const f16x8*)(&Abuf[AB(rb, kt, mt, ln, 0)]);
#pragma unroll
      for (int mt = 0; mt < 2; ++mt)
#pragma unroll
        for (int nt = 0; nt < 4; ++nt)
          acc[mt][nt] = __builtin_amdgcn_mfma_f32_16x16x32_f16(Af[mt], Bh[kt][nt], acc[mt][nt], 0, 0, 0);
    }
    epilogue(bPr, true, rb, wb);
    __syncthreads();  // barrier B: h_{s+1} visible
    {                 // output projection partials
      int row = tid & 31, jj = (tid >> 5) & 1, seg = tid >> 6;  // seg 0..7
      int kt2 = seg >> 1;
      int qA = 2 * (seg & 1);
      f16x8 hA = *(const f16x8*)(&Abuf[AB(wb, kt2, (row >> 4), (row & 15) + 16 * qA, 0)]);
      f16x8 hB = *(const f16x8*)(&Abuf[AB(wb, kt2, (row >> 4), (row & 15) + 16 * (qA + 1), 0)]);
      const float* wo = W_out + jj * 128 + seg * 16;
      float sacc = 0.f;
#pragma unroll
      for (int u = 0; u < 8; ++u) sacc += wo[u] * (float)hA[u];
#pragma unroll
      for (int u = 0; u < 8; ++u) sacc += wo[8 + u] * (float)hB[u];
      red[jj][row][seg] = sacc;
    }
    __syncthreads();  // barrier C
    if (tid < 64) {
      int row = tid >> 1, jj = tid & 1;
      float d = b_out[jj];
#pragma unroll
      for (int sg = 0; sg < 8; ++sg) d += red[jj][row][sg];
      out[((size_t)(b0 + row)) * (PREDL * 2) + p * 2 + jj] = d;
      xybuf[wb][row][jj] = d;  // prev-disp for next step
    }
  }
}

// ---------------------------------------------------------------------------
extern "C" void kernel_launch(void* const* d_in, const int* in_sizes, int n_in,
                              void* d_out, int out_size, void* d_ws, size_t ws_size,
                              hipStream_t stream) {
  const float* obs   = (const float*)d_in[0];
  const float* nbrs  = (const float*)d_in[1];
  const float* table = (const float*)d_in[2];
  const float* W_in  = (const float*)d_in[3];
  const float* b_in  = (const float*)d_in[4];
  const float* W_sp  = (const float*)d_in[5];
  const float* b_sp  = (const float*)d_in[6];
  const float* W_ih  = (const float*)d_in[7];
  const float* W_hh  = (const float*)d_in[8];
  const float* b_ih  = (const float*)d_in[9];
  const float* b_hh  = (const float*)d_in[10];
  const float* W_out = (const float*)d_in[11];
  const float* b_out = (const float*)d_in[12];
  float* out = (float*)d_out;

  // ws layout (bytes):
  //   Wfrag f16[81920]        @0       (163840)
  //   biasO f32[512]          @163840
  //   biasP f32[512]          @165888
  //   wio   f32[1024]         @167936
  //   Wsp_t f32[2048]         @172032
  //   cntx  f16[16384*8*32]   @180224  (8388608)
  char* ws = (char*)d_ws;
  f16*   Wfrag  = (f16*)(ws);
  float* biasO  = (float*)(ws + 163840);
  float* biasP  = (float*)(ws + 165888);
  float* wio    = (float*)(ws + 167936);
  float* Wsp_t  = (float*)(ws + 172032);
  f16*   cntx   = (f16*)(ws + 180224);

  wsp_t_kernel<<<8, 256, 0, stream>>>(W_sp, table, Wsp_t);
  pack_w_kernel<<<320, 256, 0, stream>>>(W_ih, W_hh, W_in, Wsp_t, Wfrag);
  pack_misc_kernel<<<8, 256, 0, stream>>>(W_ih, W_in, b_in, b_sp, b_ih, b_hh, biasO, biasP, wio);
  pool_kernel<<<Bsz / 4, 256, 0, stream>>>(obs, nbrs, cntx);
  social_lstm_main<<<Bsz / MR, 512, 0, stream>>>(Wfrag, biasO, biasP, wio, cntx,
                                                 W_out, b_out, out);
}

// Round 4
// 209.186 us; speedup vs baseline: 1.4483x; 1.4483x over previous
//
#include <hip/hip_runtime.h>
#include <math.h>

typedef _Float16 f16;
typedef f16 f16x8 __attribute__((ext_vector_type(8)));
typedef float f32x4 __attribute__((ext_vector_type(4)));

#define Bsz   16384
#define Tobs  8
#define PREDL 12
#define MR    32   // batch rows per main block

__device__ __forceinline__ float fast_sigm(float x) {
  float e = __builtin_amdgcn_exp2f(-1.44269504f * x);
  return __builtin_amdgcn_rcpf(1.f + e);
}
__device__ __forceinline__ float fast_tanh(float x) {
  float e = __builtin_amdgcn_exp2f(2.88539008f * x);  // e^(2x)
  return 1.f - 2.f * __builtin_amdgcn_rcpf(1.f + e);
}

// Abuf index: [buf(2)][kt(4)][mt(2)][lane(64)][j(8)] f16
#define AB(buf, kt, mt, lane, j) (((((buf)*4 + (kt))*2 + (mt))*64 + (lane))*8 + (j))

// Wfrag fragment slot: [ktw(9)][w(8)][nt(4)][lane(64)][j(8)] f16
// ktw 0..3: W_hh ; ktw 4: extras [cells(16)|wio(2)|0...] ; ktw 5..8: W_eff
#define WF(ktw, w, nt, lane) ((size_t)((((ktw)*8 + (w))*4 + (nt))*64 + (lane)) * 8)

// ---------------------------------------------------------------------------
// Wsp_t[c][m] = sum_e W_sp[m][e] * table[c][e]
// ---------------------------------------------------------------------------
__global__ void wsp_t_kernel(const float* __restrict__ W_sp, const float* __restrict__ table,
                             float* __restrict__ Wsp_t) {
  int gid = blockIdx.x * 256 + threadIdx.x;
  if (gid >= 16 * 128) return;
  int c = gid >> 7, m = gid & 127;
  float s = 0.f;
  for (int e = 0; e < 32; ++e) s += W_sp[m * 32 + e] * table[c * 32 + e];
  Wsp_t[c * 128 + m] = s;
}

// ---------------------------------------------------------------------------
// pack_all: one single-wave block per gate-row jo (512 blocks).
// Coalesced row loads + butterfly reductions. Emits:
//   Wfrag ktw0..3 = W_hh, ktw4 = extras, ktw5..8 = W_eff = W_hh + wio (x) W_out
//   biasO (obs), biasP (pred step 0), biasPE (pred steps >=1, folds wio.b_out)
// ---------------------------------------------------------------------------
__global__ __launch_bounds__(64) void pack_all(
    const float* __restrict__ W_ih, const float* __restrict__ W_hh,
    const float* __restrict__ W_in, const float* __restrict__ Wsp_t,
    const float* __restrict__ b_in, const float* __restrict__ b_sp,
    const float* __restrict__ b_ih, const float* __restrict__ b_hh,
    const float* __restrict__ W_out, const float* __restrict__ b_out,
    f16* __restrict__ Wfrag, float* __restrict__ biasO,
    float* __restrict__ biasP, float* __restrict__ biasPE) {
  const int blk = blockIdx.x;            // 0..511
  const int nt = blk >> 7, w = (blk >> 4) & 7, l = blk & 15;
  const int jo = nt * 128 + w * 16 + l;  // original gate row
  const int m = threadIdx.x;             // 0..63
  __shared__ float st[256];              // hh[128] | eff[128]

  float a0 = W_ih[jo * 256 + m],        a1 = W_ih[jo * 256 + 64 + m];
  float s0 = W_ih[jo * 256 + 128 + m],  s1 = W_ih[jo * 256 + 192 + m];
  float hh0 = W_hh[jo * 128 + m],       hh1 = W_hh[jo * 128 + 64 + m];
  float bi0 = b_in[m], bi1 = b_in[64 + m];
  float bs0 = b_sp[m], bs1 = b_sp[64 + m];
  float wi00 = W_in[m * 2 + 0],        wi01 = W_in[m * 2 + 1];
  float wi10 = W_in[(64 + m) * 2 + 0], wi11 = W_in[(64 + m) * 2 + 1];
  float wo00 = W_out[m],       wo01 = W_out[64 + m];        // W_out[0][*]
  float wo10 = W_out[128 + m], wo11 = W_out[192 + m];       // W_out[1][*]

  auto red = [](float v) {
#pragma unroll
    for (int s = 1; s < 64; s <<= 1) v += __shfl_xor(v, s);
    return v;
  };

  float cells[16];
#pragma unroll
  for (int c = 0; c < 16; ++c)
    cells[c] = red(s0 * Wsp_t[c * 128 + m] + s1 * Wsp_t[c * 128 + 64 + m]);
  float wio0 = red(a0 * wi00 + a1 * wi10);
  float wio1 = red(a0 * wi01 + a1 * wi11);
  float dotA = red(a0 * bi0 + a1 * bi1);
  float dotS = red(s0 * bs0 + s1 * bs1);

  st[m] = hh0;
  st[64 + m] = hh1;
  st[128 + m] = hh0 + wio0 * wo00 + wio1 * wo10;
  st[192 + m] = hh1 + wio0 * wo01 + wio1 * wo11;
  __syncthreads();

  if (m < 32) {  // W_hh (which=0) and W_eff (which=1) fragment writes
    int u = m & 15, kt = u >> 2, q = u & 3;
    int which = m >> 4;
    int ktw = which ? kt + 5 : kt;
    f16x8 v;
#pragma unroll
    for (int j = 0; j < 8; ++j) v[j] = (f16)st[which * 128 + kt * 32 + q * 8 + j];
    *(f16x8*)(Wfrag + WF(ktw, w, nt, q * 16 + l)) = v;
  } else if (m < 36) {  // extras tile ktw=4, q = m-32
    int q = m - 32;
    f16x8 v;
#pragma unroll
    for (int j = 0; j < 8; ++j) {
      int kk = q * 8 + j;
      float x = (kk < 16) ? cells[kk] : (kk == 16 ? wio0 : (kk == 17 ? wio1 : 0.f));
      v[j] = (f16)x;
    }
    *(f16x8*)(Wfrag + WF(4, w, nt, q * 16 + l)) = v;
  } else if (m == 36) {
    int col = w * 64 + nt * 16 + l;  // permuted column index
    float base = b_ih[jo] + b_hh[jo];
    biasO[col] = base + dotA + dotS;
    float bp = base + dotA;
    biasP[col] = bp;
    biasPE[col] = bp + wio0 * b_out[0] + wio1 * b_out[1];
  }
}

// ---------------------------------------------------------------------------
// Pool: one wave per batch element; lane = neighbor. Ballot+popcount counts.
// cntx[b][t][32] = [cnt(16) | obs xy (2) | untouched]
// ---------------------------------------------------------------------------
__global__ __launch_bounds__(256) void pool_kernel(const float* __restrict__ obs,
                                                   const float* __restrict__ nb,
                                                   f16* __restrict__ cntx) {
  int tid = threadIdx.x;
  int wv = tid >> 6, ln = tid & 63;
  int b = blockIdx.x * 4 + wv;
  const float4* nb4 = (const float4*)(nb + (((size_t)b * 64 + ln) * 8) * 2);
  float4 n0 = nb4[0], n1 = nb4[1], n2 = nb4[2], n3 = nb4[3];
  const float4* ob4 = (const float4*)(obs + (size_t)b * 16);
  float4 o0 = ob4[0], o1 = ob4[1], o2 = ob4[2], o3 = ob4[3];
  float nxv[8] = {n0.x, n0.z, n1.x, n1.z, n2.x, n2.z, n3.x, n3.z};
  float nyv[8] = {n0.y, n0.w, n1.y, n1.w, n2.y, n2.w, n3.y, n3.w};
  float oxv[8] = {o0.x, o0.z, o1.x, o1.z, o2.x, o2.z, o3.x, o3.z};
  float oyv[8] = {o0.y, o0.w, o1.y, o1.w, o2.y, o2.w, o3.y, o3.w};
  int flat[8];
#pragma unroll
  for (int t = 0; t < 8; ++t) {
    float rx = nxv[t] - oxv[t], ry = nyv[t] - oyv[t];
    int ix = (int)floorf(rx + rx);
    int iy = (int)floorf(ry + ry);
    ix = min(max(ix, -2), 1);
    iy = min(max(iy, -2), 1);
    flat[t] = (ix + 2) * 4 + (iy + 2);
  }
  int cnt0 = 0, cnt1 = 0;
#pragma unroll
  for (int t = 0; t < 8; ++t) {
#pragma unroll
    for (int c = 0; c < 16; ++c) {
      int n = (int)__popcll(__ballot(flat[t] == c));
      if (t < 4) cnt0 = (ln == t * 16 + c) ? n : cnt0;
      else       cnt1 = (ln == (t - 4) * 16 + c) ? n : cnt1;
    }
  }
  int myT = ln >> 4, myC = ln & 15;
  size_t base = (size_t)b * 8;
  cntx[(base + myT) * 32 + myC] = (f16)cnt0;
  cntx[(base + myT + 4) * 32 + myC] = (f16)cnt1;
  if (ln < 8) {
    float ox2 = obs[base * 2 + ln * 2], oy2 = obs[base * 2 + ln * 2 + 1];
    cntx[(base + ln) * 32 + 16] = (f16)ox2;
    cntx[(base + ln) * 32 + 17] = (f16)oy2;
  }
}

// ---------------------------------------------------------------------------
// Main: 32 rows/block, 512 threads, W_hh/W_eff frags in VGPRs,
// 1 barrier per step (disp output off the critical path via W_eff fold).
// ---------------------------------------------------------------------------
__global__ __launch_bounds__(512, 2) void social_lstm_main(
    const f16* __restrict__ Wfrag, const float* __restrict__ biasO,
    const float* __restrict__ biasP, const float* __restrict__ biasPE,
    const f16* __restrict__ cntx, const float* __restrict__ W_out,
    const float* __restrict__ b_out, float* __restrict__ out) {
  __shared__ __align__(16) f16 Abuf[2 * 4 * 2 * 64 * 8];  // 16 KB

  const int tid = threadIdx.x;
  const int w = tid >> 6, ln = tid & 63;
  const int q = ln >> 4, l = ln & 15;
  const int b0 = blockIdx.x * MR;

  for (int i = tid; i < 2048; i += 512) ((uint32_t*)Abuf)[i] = 0u;  // zero buf 0

  // persistent W_hh B fragments
  f16x8 Bh[4][4];
#pragma unroll
  for (int kt = 0; kt < 4; ++kt)
#pragma unroll
    for (int nt = 0; nt < 4; ++nt)
      Bh[kt][nt] = *(const f16x8*)(Wfrag + WF(kt, w, nt, ln));
  // extras B fragments (obs phase only)
  f16x8 Bx[4];
#pragma unroll
  for (int nt = 0; nt < 4; ++nt) Bx[nt] = *(const f16x8*)(Wfrag + WF(4, w, nt, ln));

  float creg[8];
#pragma unroll
  for (int i = 0; i < 8; ++i) creg[i] = 0.f;

  float bOr[4], bPr[4];
#pragma unroll
  for (int g = 0; g < 4; ++g) {
    bOr[g] = biasO[w * 64 + g * 16 + l];
    bPr[g] = biasP[w * 64 + g * 16 + l];
  }

  const int hc = w * 16 + l;
  const int aw_kt = hc >> 5, aw_quad = (hc >> 3) & 3, aw_j = l & 7;

  f32x4 acc[2][4];

  auto gemm_h = [&](int rb) {
#pragma unroll
    for (int kt = 0; kt < 4; ++kt) {
      f16x8 Af[2];
#pragma unroll
      for (int mt = 0; mt < 2; ++mt) Af[mt] = *(const f16x8*)(&Abuf[AB(rb, kt, mt, ln, 0)]);
#pragma unroll
      for (int mt = 0; mt < 2; ++mt)
#pragma unroll
        for (int nt = 0; nt < 4; ++nt)
          acc[mt][nt] =
              __builtin_amdgcn_mfma_f32_16x16x32_f16(Af[mt], Bh[kt][nt], acc[mt][nt], 0, 0, 0);
    }
  };

  auto epilogue = [&](const float* bq, int wbuf) {
#pragma unroll
    for (int mt = 0; mt < 2; ++mt) {
#pragma unroll
      for (int reg = 0; reg < 4; ++reg) {
        float p0 = acc[mt][0][reg] + bq[0];
        float p1 = acc[mt][1][reg] + bq[1];
        float p2 = acc[mt][2][reg] + bq[2];
        float p3 = acc[mt][3][reg] + bq[3];
        float iv = fast_sigm(p0), fv = fast_sigm(p1);
        float gv = fast_tanh(p2), ov = fast_sigm(p3);
        int ci = mt * 4 + reg;
        float c2 = fv * creg[ci] + iv * gv;
        creg[ci] = c2;
        float hv = ov * fast_tanh(c2);
        Abuf[AB(wbuf, aw_kt, mt, (q * 4 + reg) + 16 * aw_quad, aw_j)] = (f16)hv;
      }
    }
  };

  // ---------------- observation phase ----------------
#pragma unroll
  for (int t = 0; t < Tobs; ++t) {
    const int rb = t & 1, wb = rb ^ 1;
    __syncthreads();
    f16x8 Ax[2];
#pragma unroll
    for (int mt = 0; mt < 2; ++mt)
      Ax[mt] = *(const f16x8*)(cntx + ((size_t)(b0 + mt * 16 + l) * Tobs + t) * 32 + q * 8);
#pragma unroll
    for (int mt = 0; mt < 2; ++mt)
#pragma unroll
      for (int nt = 0; nt < 4; ++nt) acc[mt][nt] = (f32x4){0.f, 0.f, 0.f, 0.f};
#pragma unroll
    for (int mt = 0; mt < 2; ++mt)
#pragma unroll
      for (int nt = 0; nt < 4; ++nt)
        acc[mt][nt] = __builtin_amdgcn_mfma_f32_16x16x32_f16(Ax[mt], Bx[nt], acc[mt][nt], 0, 0, 0);
    gemm_h(rb);
    epilogue(bOr, wb);
  }

  // ---------------- prediction step 0 (prev disp = 0, plain W_hh) ----------
  {
    const int rb = Tobs & 1, wb = rb ^ 1;  // rb=0, wb=1
    __syncthreads();
#pragma unroll
    for (int mt = 0; mt < 2; ++mt)
#pragma unroll
      for (int nt = 0; nt < 4; ++nt) acc[mt][nt] = (f32x4){0.f, 0.f, 0.f, 0.f};
    gemm_h(rb);
    epilogue(bPr, wb);
  }

  // swap to W_eff + biasPE; preload W_out dot registers for disp output
#pragma unroll
  for (int kt = 0; kt < 4; ++kt)
#pragma unroll
    for (int nt = 0; nt < 4; ++nt)
      Bh[kt][nt] = *(const f16x8*)(Wfrag + WF(kt + 5, w, nt, ln));
  float bEr[4];
#pragma unroll
  for (int g = 0; g < 4; ++g) bEr[g] = biasPE[w * 64 + g * 16 + l];

  const int d_oi = tid >> 3, d_seg = tid & 7;
  const int d_row = d_oi >> 1, d_jj = d_oi & 1;
  const int d_kt = d_seg >> 1, d_q0 = (d_seg & 1) * 2;
  float wor[16];
  {
    const float4* wp = (const float4*)(W_out + d_jj * 128 + d_seg * 16);
#pragma unroll
    for (int u = 0; u < 4; ++u) {
      float4 v = wp[u];
      wor[4 * u] = v.x; wor[4 * u + 1] = v.y; wor[4 * u + 2] = v.z; wor[4 * u + 3] = v.w;
    }
  }
  const float d_bo = b_out[d_jj];

  auto disp_out = [&](int rbuf, int p) {
    f16x8 hA = *(const f16x8*)(&Abuf[AB(rbuf, d_kt, d_row >> 4, (d_row & 15) + 16 * d_q0, 0)]);
    f16x8 hB = *(const f16x8*)(&Abuf[AB(rbuf, d_kt, d_row >> 4, (d_row & 15) + 16 * (d_q0 + 1), 0)]);
    float s = 0.f;
#pragma unroll
    for (int u = 0; u < 8; ++u) s += wor[u] * (float)hA[u];
#pragma unroll
    for (int u = 0; u < 8; ++u) s += wor[8 + u] * (float)hB[u];
    s += __shfl_xor(s, 1);
    s += __shfl_xor(s, 2);
    s += __shfl_xor(s, 4);
    if ((tid & 7) == 0)
      out[((size_t)(b0 + d_row)) * (PREDL * 2) + p * 2 + d_jj] = s + d_bo;
  };

  // ---------------- prediction steps 1..11 (pure h recurrence) -------------
  for (int p = 1; p < PREDL; ++p) {
    const int s = Tobs + p;
    const int rb = s & 1, wb = rb ^ 1;
    __syncthreads();
    disp_out(rb, p - 1);  // h_{p-1} lives in Abuf[rb]
#pragma unroll
    for (int mt = 0; mt < 2; ++mt)
#pragma unroll
      for (int nt = 0; nt < 4; ++nt) acc[mt][nt] = (f32x4){0.f, 0.f, 0.f, 0.f};
    gemm_h(rb);
    epilogue(bEr, wb);
  }
  __syncthreads();
  disp_out((Tobs + PREDL) & 1, PREDL - 1);  // h_11 in buf 0
}

// ---------------------------------------------------------------------------
extern "C" void kernel_launch(void* const* d_in, const int* in_sizes, int n_in,
                              void* d_out, int out_size, void* d_ws, size_t ws_size,
                              hipStream_t stream) {
  const float* obs   = (const float*)d_in[0];
  const float* nbrs  = (const float*)d_in[1];
  const float* table = (const float*)d_in[2];
  const float* W_in  = (const float*)d_in[3];
  const float* b_in  = (const float*)d_in[4];
  const float* W_sp  = (const float*)d_in[5];
  const float* b_sp  = (const float*)d_in[6];
  const float* W_ih  = (const float*)d_in[7];
  const float* W_hh  = (const float*)d_in[8];
  const float* b_ih  = (const float*)d_in[9];
  const float* b_hh  = (const float*)d_in[10];
  const float* W_out = (const float*)d_in[11];
  const float* b_out = (const float*)d_in[12];
  float* out = (float*)d_out;

  // ws layout (bytes):
  //   Wfrag f16[9*8*4*64*8 = 147456] @0        (294912)
  //   biasO  f32[512]                @294912
  //   biasP  f32[512]                @296960
  //   biasPE f32[512]                @299008
  //   Wsp_t  f32[2048]               @301056
  //   cntx   f16[16384*8*32]         @311296   (8388608)
  char* ws = (char*)d_ws;
  f16*   Wfrag  = (f16*)(ws);
  float* biasO  = (float*)(ws + 294912);
  float* biasP  = (float*)(ws + 296960);
  float* biasPE = (float*)(ws + 299008);
  float* Wsp_t  = (float*)(ws + 301056);
  f16*   cntx   = (f16*)(ws + 311296);

  wsp_t_kernel<<<8, 256, 0, stream>>>(W_sp, table, Wsp_t);
  pack_all<<<512, 64, 0, stream>>>(W_ih, W_hh, W_in, Wsp_t, b_in, b_sp, b_ih, b_hh,
                                   W_out, b_out, Wfrag, biasO, biasP, biasPE);
  pool_kernel<<<Bsz / 4, 256, 0, stream>>>(obs, nbrs, cntx);
  social_lstm_main<<<Bsz / MR, 512, 0, stream>>>(Wfrag, biasO, biasP, biasPE, cntx,
                                                 W_out, b_out, out);
}

// Round 5
// 205.664 us; speedup vs baseline: 1.4731x; 1.0171x over previous
//
#include <hip/hip_runtime.h>
#include <math.h>

typedef _Float16 f16;
typedef f16 f16x8 __attribute__((ext_vector_type(8)));
typedef float f32x4 __attribute__((ext_vector_type(4)));

#define Bsz   16384
#define Tobs  8
#define PREDL 12
#define MR    32   // batch rows per main block

__device__ __forceinline__ float fast_sigm(float x) {
  float e = __builtin_amdgcn_exp2f(-1.44269504f * x);
  return __builtin_amdgcn_rcpf(1.f + e);
}
__device__ __forceinline__ float fast_tanh(float x) {
  float e = __builtin_amdgcn_exp2f(2.88539008f * x);  // e^(2x)
  return 1.f - 2.f * __builtin_amdgcn_rcpf(1.f + e);
}

// Abuf index: [buf(2)][kt(4)][mt(2)][lane(64)][j(8)] f16
#define AB(buf, kt, mt, lane, j) (((((buf)*4 + (kt))*2 + (mt))*64 + (lane))*8 + (j))
// cntA index: [t(8)][mt(2)][lane(64)][j(8)] f16
#define CA(t, mt, lane, j) ((((t)*2 + (mt))*64 + (lane))*8 + (j))

// Wfrag fragment slot: [ktw(9)][w(8)][nt(4)][lane(64)][j(8)] f16
// ktw 0..3: W_hh ; ktw 4: extras [cells(16)|wio(2)|0...] ; ktw 5..8: W_eff
#define WF(ktw, w, nt, lane) ((size_t)((((ktw)*8 + (w))*4 + (nt))*64 + (lane)) * 8)

// ---------------------------------------------------------------------------
// pack_all: one single-wave block per gate-row jo (512 blocks).
// Folds wsp_t: cells[c] = sum_e table[c][e] * wspP[e],
//   wspP[e] = sum_m W_ih[jo][128+m] * W_sp[m][e].
// Emits Wfrag (W_hh | extras | W_eff = W_hh + wio (x) W_out) and the 3 biases.
// ---------------------------------------------------------------------------
__global__ __launch_bounds__(64) void pack_all(
    const float* __restrict__ W_ih, const float* __restrict__ W_hh,
    const float* __restrict__ W_in, const float* __restrict__ W_sp,
    const float* __restrict__ table,
    const float* __restrict__ b_in, const float* __restrict__ b_sp,
    const float* __restrict__ b_ih, const float* __restrict__ b_hh,
    const float* __restrict__ W_out, const float* __restrict__ b_out,
    f16* __restrict__ Wfrag, float* __restrict__ biasO,
    float* __restrict__ biasP, float* __restrict__ biasPE) {
  const int blk = blockIdx.x;            // 0..511
  const int nt = blk >> 7, w = (blk >> 4) & 7, l = blk & 15;
  const int jo = nt * 128 + w * 16 + l;  // original gate row
  const int m = threadIdx.x;             // 0..63
  __shared__ float st[256];              // hh[128] | eff[128]
  __shared__ float wspPS[32];
  __shared__ float cellsS[16];

  float a0 = W_ih[jo * 256 + m],        a1 = W_ih[jo * 256 + 64 + m];
  float s0 = W_ih[jo * 256 + 128 + m],  s1 = W_ih[jo * 256 + 192 + m];
  float hh0 = W_hh[jo * 128 + m],       hh1 = W_hh[jo * 128 + 64 + m];
  float bi0 = b_in[m], bi1 = b_in[64 + m];
  float bs0 = b_sp[m], bs1 = b_sp[64 + m];
  float wi00 = W_in[m * 2 + 0],        wi01 = W_in[m * 2 + 1];
  float wi10 = W_in[(64 + m) * 2 + 0], wi11 = W_in[(64 + m) * 2 + 1];
  float wo00 = W_out[m],       wo01 = W_out[64 + m];        // W_out[0][*]
  float wo10 = W_out[128 + m], wo11 = W_out[192 + m];       // W_out[1][*]

  auto red = [](float v) {
#pragma unroll
    for (int s = 1; s < 64; s <<= 1) v += __shfl_xor(v, s);
    return v;
  };

  // wspP[e] via butterfly reductions
#pragma unroll 4
  for (int e = 0; e < 32; ++e) {
    float wp = red(s0 * W_sp[m * 32 + e] + s1 * W_sp[(64 + m) * 32 + e]);
    if (m == e) wspPS[e] = wp;
  }
  __syncthreads();
  if (m < 16) {
    float s = 0.f;
#pragma unroll
    for (int e = 0; e < 32; ++e) s += table[m * 32 + e] * wspPS[e];
    cellsS[m] = s;
  }

  float wio0 = red(a0 * wi00 + a1 * wi10);
  float wio1 = red(a0 * wi01 + a1 * wi11);
  float dotA = red(a0 * bi0 + a1 * bi1);
  float dotS = red(s0 * bs0 + s1 * bs1);

  st[m] = hh0;
  st[64 + m] = hh1;
  st[128 + m] = hh0 + wio0 * wo00 + wio1 * wo10;
  st[192 + m] = hh1 + wio0 * wo01 + wio1 * wo11;
  __syncthreads();

  if (m < 32) {  // W_hh (which=0) and W_eff (which=1) fragment writes
    int u = m & 15, kt = u >> 2, q = u & 3;
    int which = m >> 4;
    int ktw = which ? kt + 5 : kt;
    f16x8 v;
#pragma unroll
    for (int j = 0; j < 8; ++j) v[j] = (f16)st[which * 128 + kt * 32 + q * 8 + j];
    *(f16x8*)(Wfrag + WF(ktw, w, nt, q * 16 + l)) = v;
  } else if (m < 36) {  // extras tile ktw=4, q = m-32
    int q = m - 32;
    f16x8 v;
#pragma unroll
    for (int j = 0; j < 8; ++j) {
      int kk = q * 8 + j;
      float x = (kk < 16) ? cellsS[kk] : (kk == 16 ? wio0 : (kk == 17 ? wio1 : 0.f));
      v[j] = (f16)x;
    }
    *(f16x8*)(Wfrag + WF(4, w, nt, q * 16 + l)) = v;
  } else if (m == 36) {
    int col = w * 64 + nt * 16 + l;  // permuted column index
    float base = b_ih[jo] + b_hh[jo];
    biasO[col] = base + dotA + dotS;
    float bp = base + dotA;
    biasP[col] = bp;
    biasPE[col] = bp + wio0 * b_out[0] + wio1 * b_out[1];
  }
}

// ---------------------------------------------------------------------------
// Main: 32 rows/block, 512 threads. Social pooling fused in (histogram via
// packed-bin u64 + shfl butterflies), W_hh/W_eff frags in VGPRs, MFMA
// recurrence with bias-initialized accumulators, 1 barrier per step.
// ---------------------------------------------------------------------------
__global__ __launch_bounds__(512, 2) void social_lstm_main(
    const float* __restrict__ obs, const float* __restrict__ nb,
    const f16* __restrict__ Wfrag, const float* __restrict__ biasO,
    const float* __restrict__ biasP, const float* __restrict__ biasPE,
    const float* __restrict__ W_out, const float* __restrict__ b_out,
    float* __restrict__ out) {
  __shared__ __align__(16) f16 Abuf[2 * 4 * 2 * 64 * 8];  // 16 KB
  __shared__ __align__(16) f16 cntA[8 * 2 * 64 * 8];      // 16 KB obs A-panels

  const int tid = threadIdx.x;
  const int w = tid >> 6, ln = tid & 63;
  const int q = ln >> 4, l = ln & 15;
  const int b0 = blockIdx.x * MR;

  // zero Abuf buf0 + all of cntA (covers channels 18..31 and padding)
  for (int i = tid; i < 2048; i += 512) ((uint32_t*)Abuf)[i] = 0u;
  for (int i = tid; i < 4096; i += 512) ((uint32_t*)cntA)[i] = 0u;
  __syncthreads();

  // ---------------- fused social pooling ----------------
  {
    const int g = ln >> 4, lg = ln & 15;
    const int r = w * 4 + g;  // local row 0..31
    const float4* orow = (const float4*)(obs + (size_t)(b0 + r) * 16);
    float4 O0 = orow[0], O1 = orow[1], O2 = orow[2], O3 = orow[3];
    float ox[8] = {O0.x, O0.z, O1.x, O1.z, O2.x, O2.z, O3.x, O3.z};
    float oy[8] = {O0.y, O0.w, O1.y, O1.w, O2.y, O2.w, O3.y, O3.w};
    unsigned long long h[8] = {0ull, 0ull, 0ull, 0ull, 0ull, 0ull, 0ull, 0ull};
#pragma unroll
    for (int jt = 0; jt < 4; ++jt) {
      const float4* tr =
          (const float4*)(nb + ((size_t)(b0 + r) * 64 + (lg + 16 * jt)) * 16);
      float4 N0 = tr[0], N1 = tr[1], N2 = tr[2], N3 = tr[3];
      float nx[8] = {N0.x, N0.z, N1.x, N1.z, N2.x, N2.z, N3.x, N3.z};
      float ny[8] = {N0.y, N0.w, N1.y, N1.w, N2.y, N2.w, N3.y, N3.w};
#pragma unroll
      for (int t = 0; t < 8; ++t) {
        float rx = nx[t] - ox[t], ry = ny[t] - oy[t];
        int ix = (int)floorf(rx + rx);
        int iy = (int)floorf(ry + ry);
        ix = min(max(ix, -2), 1);
        iy = min(max(iy, -2), 1);
        int flat = (ix + 2) * 4 + (iy + 2);   // 0..15, count per lane <= 4
        h[t] += 1ull << (flat * 4);           // 4-bit bins
      }
    }
    auto shx = [](unsigned long long x, int msk) {
      unsigned lo = __shfl_xor((unsigned)x, msk);
      unsigned hi = __shfl_xor((unsigned)(x >> 32), msk);
      return ((unsigned long long)hi << 32) | lo;
    };
#pragma unroll
    for (int t = 0; t < 8; ++t) {
      unsigned long long v = h[t];
      v += shx(v, 1);  // sums <= 8, still fits 4-bit bins
      unsigned long long e0 = v & 0x0F0F0F0F0F0F0F0Full;         // even bins, 8-bit
      unsigned long long e1 = (v >> 4) & 0x0F0F0F0F0F0F0F0Full;  // odd bins
      e0 += shx(e0, 2); e1 += shx(e1, 2);
      e0 += shx(e0, 4); e1 += shx(e1, 4);
      e0 += shx(e0, 8); e1 += shx(e1, 8);
      unsigned long long wsel = (lg & 1) ? e1 : e0;
      unsigned cnt = (unsigned)(wsel >> ((lg >> 1) * 8)) & 0xFFu;
      // channel c = lg -> slot lane (lg>>3)*16 + (r&15), j = lg&7
      cntA[CA(t, r >> 4, (lg >> 3) * 16 + (r & 15), lg & 7)] = (f16)(float)cnt;
    }
    // xy channels 16,17
    int rr = tid >> 4, tt = (tid >> 1) & 7, comp = tid & 1;
    float xv = obs[(size_t)(b0 + rr) * 16 + tt * 2 + comp];
    cntA[CA(tt, rr >> 4, 2 * 16 + (rr & 15), comp)] = (f16)xv;
  }
  __builtin_amdgcn_sched_barrier(0);  // keep weight loads below the pooling phase

  // persistent W_hh B fragments + extras
  f16x8 Bh[4][4];
#pragma unroll
  for (int kt = 0; kt < 4; ++kt)
#pragma unroll
    for (int nt = 0; nt < 4; ++nt)
      Bh[kt][nt] = *(const f16x8*)(Wfrag + WF(kt, w, nt, ln));
  f16x8 Bx[4];
#pragma unroll
  for (int nt = 0; nt < 4; ++nt) Bx[nt] = *(const f16x8*)(Wfrag + WF(4, w, nt, ln));

  float creg[8];
#pragma unroll
  for (int i = 0; i < 8; ++i) creg[i] = 0.f;

  float bOr[4], bPr[4];
#pragma unroll
  for (int g2 = 0; g2 < 4; ++g2) {
    bOr[g2] = biasO[w * 64 + g2 * 16 + l];
    bPr[g2] = biasP[w * 64 + g2 * 16 + l];
  }

  const int hc = w * 16 + l;
  const int aw_kt = hc >> 5, aw_quad = (hc >> 3) & 3, aw_j = l & 7;

  f32x4 acc[2][4];

  auto acc_init = [&](const float* bq) {  // bias lives in C (lane-constant)
#pragma unroll
    for (int mt = 0; mt < 2; ++mt)
#pragma unroll
      for (int nt = 0; nt < 4; ++nt)
        acc[mt][nt] = (f32x4){bq[nt], bq[nt], bq[nt], bq[nt]};
  };

  auto gemm_h = [&](int rb) {
#pragma unroll
    for (int kt = 0; kt < 4; ++kt) {
      f16x8 Af[2];
#pragma unroll
      for (int mt = 0; mt < 2; ++mt) Af[mt] = *(const f16x8*)(&Abuf[AB(rb, kt, mt, ln, 0)]);
#pragma unroll
      for (int mt = 0; mt < 2; ++mt)
#pragma unroll
        for (int nt = 0; nt < 4; ++nt)
          acc[mt][nt] =
              __builtin_amdgcn_mfma_f32_16x16x32_f16(Af[mt], Bh[kt][nt], acc[mt][nt], 0, 0, 0);
    }
  };

  auto epilogue = [&](int wbuf) {
#pragma unroll
    for (int mt = 0; mt < 2; ++mt) {
#pragma unroll
      for (int reg = 0; reg < 4; ++reg) {
        float p0 = acc[mt][0][reg];
        float p1 = acc[mt][1][reg];
        float p2 = acc[mt][2][reg];
        float p3 = acc[mt][3][reg];
        float iv = fast_sigm(p0), fv = fast_sigm(p1);
        float gv = fast_tanh(p2), ov = fast_sigm(p3);
        int ci = mt * 4 + reg;
        float c2 = fv * creg[ci] + iv * gv;
        creg[ci] = c2;
        float hv = ov * fast_tanh(c2);
        Abuf[AB(wbuf, aw_kt, mt, (q * 4 + reg) + 16 * aw_quad, aw_j)] = (f16)hv;
      }
    }
  };

  // ---------------- observation phase ----------------
#pragma unroll
  for (int t = 0; t < Tobs; ++t) {
    const int rb = t & 1, wb = rb ^ 1;
    __syncthreads();
    f16x8 Ax[2];
#pragma unroll
    for (int mt = 0; mt < 2; ++mt) Ax[mt] = *(const f16x8*)(&cntA[CA(t, mt, ln, 0)]);
    acc_init(bOr);
#pragma unroll
    for (int mt = 0; mt < 2; ++mt)
#pragma unroll
      for (int nt = 0; nt < 4; ++nt)
        acc[mt][nt] = __builtin_amdgcn_mfma_f32_16x16x32_f16(Ax[mt], Bx[nt], acc[mt][nt], 0, 0, 0);
    gemm_h(rb);
    epilogue(wb);
  }

  // ---------------- prediction step 0 (prev disp = 0, plain W_hh) ----------
  {
    const int rb = Tobs & 1, wb = rb ^ 1;  // rb=0, wb=1
    __syncthreads();
    acc_init(bPr);
    gemm_h(rb);
    epilogue(wb);
  }

  // swap to W_eff + biasPE; preload W_out dot registers for disp output
#pragma unroll
  for (int kt = 0; kt < 4; ++kt)
#pragma unroll
    for (int nt = 0; nt < 4; ++nt)
      Bh[kt][nt] = *(const f16x8*)(Wfrag + WF(kt + 5, w, nt, ln));
  float bEr[4];
#pragma unroll
  for (int g2 = 0; g2 < 4; ++g2) bEr[g2] = biasPE[w * 64 + g2 * 16 + l];

  const int d_oi = tid >> 3, d_seg = tid & 7;
  const int d_row = d_oi >> 1, d_jj = d_oi & 1;
  const int d_kt = d_seg >> 1, d_q0 = (d_seg & 1) * 2;
  float wor[16];
  {
    const float4* wp = (const float4*)(W_out + d_jj * 128 + d_seg * 16);
#pragma unroll
    for (int u = 0; u < 4; ++u) {
      float4 v = wp[u];
      wor[4 * u] = v.x; wor[4 * u + 1] = v.y; wor[4 * u + 2] = v.z; wor[4 * u + 3] = v.w;
    }
  }
  const float d_bo = b_out[d_jj];

  auto disp_out = [&](int rbuf, int p) {
    f16x8 hA = *(const f16x8*)(&Abuf[AB(rbuf, d_kt, d_row >> 4, (d_row & 15) + 16 * d_q0, 0)]);
    f16x8 hB = *(const f16x8*)(&Abuf[AB(rbuf, d_kt, d_row >> 4, (d_row & 15) + 16 * (d_q0 + 1), 0)]);
    float s = 0.f;
#pragma unroll
    for (int u = 0; u < 8; ++u) s += wor[u] * (float)hA[u];
#pragma unroll
    for (int u = 0; u < 8; ++u) s += wor[8 + u] * (float)hB[u];
    s += __shfl_xor(s, 1);
    s += __shfl_xor(s, 2);
    s += __shfl_xor(s, 4);
    if ((tid & 7) == 0)
      out[((size_t)(b0 + d_row)) * (PREDL * 2) + p * 2 + d_jj] = s + d_bo;
  };

  // ---------------- prediction steps 1..11 (pure h recurrence) -------------
  for (int p = 1; p < PREDL; ++p) {
    const int s = Tobs + p;
    const int rb = s & 1, wb = rb ^ 1;
    __syncthreads();
    disp_out(rb, p - 1);  // h_{p-1} lives in Abuf[rb]
    acc_init(bEr);
    gemm_h(rb);
    epilogue(wb);
  }
  __syncthreads();
  disp_out((Tobs + PREDL) & 1, PREDL - 1);  // h_11 in buf 0
}

// ---------------------------------------------------------------------------
extern "C" void kernel_launch(void* const* d_in, const int* in_sizes, int n_in,
                              void* d_out, int out_size, void* d_ws, size_t ws_size,
                              hipStream_t stream) {
  const float* obs   = (const float*)d_in[0];
  const float* nbrs  = (const float*)d_in[1];
  const float* table = (const float*)d_in[2];
  const float* W_in  = (const float*)d_in[3];
  const float* b_in  = (const float*)d_in[4];
  const float* W_sp  = (const float*)d_in[5];
  const float* b_sp  = (const float*)d_in[6];
  const float* W_ih  = (const float*)d_in[7];
  const float* W_hh  = (const float*)d_in[8];
  const float* b_ih  = (const float*)d_in[9];
  const float* b_hh  = (const float*)d_in[10];
  const float* W_out = (const float*)d_in[11];
  const float* b_out = (const float*)d_in[12];
  float* out = (float*)d_out;

  // ws layout (bytes):
  //   Wfrag f16[9*8*4*64*8 = 147456] @0        (294912)
  //   biasO  f32[512]                @294912
  //   biasP  f32[512]                @296960
  //   biasPE f32[512]                @299008
  char* ws = (char*)d_ws;
  f16*   Wfrag  = (f16*)(ws);
  float* biasO  = (float*)(ws + 294912);
  float* biasP  = (float*)(ws + 296960);
  float* biasPE = (float*)(ws + 299008);

  pack_all<<<512, 64, 0, stream>>>(W_ih, W_hh, W_in, W_sp, table, b_in, b_sp, b_ih, b_hh,
                                   W_out, b_out, Wfrag, biasO, biasP, biasPE);
  social_lstm_main<<<Bsz / MR, 512, 0, stream>>>(obs, nbrs, Wfrag, biasO, biasP, biasPE,
                                                 W_out, b_out, out);
}

// Round 6
// 205.369 us; speedup vs baseline: 1.4752x; 1.0014x over previous
//
#include <hip/hip_runtime.h>
#include <math.h>

typedef _Float16 f16;
typedef f16 f16x8 __attribute__((ext_vector_type(8)));
typedef float f32x4 __attribute__((ext_vector_type(4)));

#define Bsz   16384
#define Tobs  8
#define PREDL 12
#define MR    32   // batch rows per main block

__device__ __forceinline__ float fast_sigm(float x) {
  float e = __builtin_amdgcn_exp2f(-1.44269504f * x);
  return __builtin_amdgcn_rcpf(1.f + e);
}
__device__ __forceinline__ float fast_tanh(float x) {
  float e = __builtin_amdgcn_exp2f(2.88539008f * x);  // e^(2x)
  return 1.f - 2.f * __builtin_amdgcn_rcpf(1.f + e);
}

// Abuf index: [buf(2)][kt(4)][mt(2)][lane(64)][j(8)] f16
#define AB(buf, kt, mt, lane, j) (((((buf)*4 + (kt))*2 + (mt))*64 + (lane))*8 + (j))
// cntA index: [t(8)][mt(2)][lane(64)][j(8)] f16
#define CA(t, mt, lane, j) ((((t)*2 + (mt))*64 + (lane))*8 + (j))

// Wfrag fragment slot: [ktw(9)][w(8)][nt(4)][lane(64)][j(8)] f16
// ktw 0..3: W_hh ; ktw 4: extras [cells(16)|wio(2)|0...] ; ktw 5..8: W_eff
#define WF(ktw, w, nt, lane) ((size_t)((((ktw)*8 + (w))*4 + (nt))*64 + (lane)) * 8)

// ---------------------------------------------------------------------------
// pack_all: one single-wave block per gate-row jo (512 blocks).
// cells[c] = sum_e table[c][e] * wspP[e],  wspP[e] = sum_m W_ih[jo][128+m]*W_sp[m][e]
// Emits Wfrag (W_hh | extras | W_eff = W_hh + wio (x) W_out) and the 3 biases.
// ---------------------------------------------------------------------------
__global__ __launch_bounds__(64) void pack_all(
    const float* __restrict__ W_ih, const float* __restrict__ W_hh,
    const float* __restrict__ W_in, const float* __restrict__ W_sp,
    const float* __restrict__ table,
    const float* __restrict__ b_in, const float* __restrict__ b_sp,
    const float* __restrict__ b_ih, const float* __restrict__ b_hh,
    const float* __restrict__ W_out, const float* __restrict__ b_out,
    f16* __restrict__ Wfrag, float* __restrict__ biasO,
    float* __restrict__ biasP, float* __restrict__ biasPE) {
  const int blk = blockIdx.x;            // 0..511
  const int nt = blk >> 7, w = (blk >> 4) & 7, l = blk & 15;
  const int jo = nt * 128 + w * 16 + l;  // original gate row
  const int m = threadIdx.x;             // 0..63
  __shared__ float st[256];              // hh[128] | eff[128]
  __shared__ float wspPS[32];
  __shared__ float cellsS[16];

  float a0 = W_ih[jo * 256 + m],        a1 = W_ih[jo * 256 + 64 + m];
  float s0 = W_ih[jo * 256 + 128 + m],  s1 = W_ih[jo * 256 + 192 + m];
  float hh0 = W_hh[jo * 128 + m],       hh1 = W_hh[jo * 128 + 64 + m];
  float bi0 = b_in[m], bi1 = b_in[64 + m];
  float bs0 = b_sp[m], bs1 = b_sp[64 + m];
  float wi00 = W_in[m * 2 + 0],        wi01 = W_in[m * 2 + 1];
  float wi10 = W_in[(64 + m) * 2 + 0], wi11 = W_in[(64 + m) * 2 + 1];
  float wo00 = W_out[m],       wo01 = W_out[64 + m];        // W_out[0][*]
  float wo10 = W_out[128 + m], wo11 = W_out[192 + m];       // W_out[1][*]

  auto red = [](float v) {
#pragma unroll
    for (int s = 1; s < 64; s <<= 1) v += __shfl_xor(v, s);
    return v;
  };

  // wspP[e] via butterfly reductions
#pragma unroll 4
  for (int e = 0; e < 32; ++e) {
    float wp = red(s0 * W_sp[m * 32 + e] + s1 * W_sp[(64 + m) * 32 + e]);
    if (m == e) wspPS[e] = wp;
  }
  __syncthreads();
  if (m < 16) {
    float s = 0.f;
#pragma unroll
    for (int e = 0; e < 32; ++e) s += table[m * 32 + e] * wspPS[e];
    cellsS[m] = s;
  }

  float wio0 = red(a0 * wi00 + a1 * wi10);
  float wio1 = red(a0 * wi01 + a1 * wi11);
  float dotA = red(a0 * bi0 + a1 * bi1);
  float dotS = red(s0 * bs0 + s1 * bs1);

  st[m] = hh0;
  st[64 + m] = hh1;
  st[128 + m] = hh0 + wio0 * wo00 + wio1 * wo10;
  st[192 + m] = hh1 + wio0 * wo01 + wio1 * wo11;
  __syncthreads();

  if (m < 32) {  // W_hh (which=0) and W_eff (which=1) fragment writes
    int u = m & 15, kt = u >> 2, q = u & 3;
    int which = m >> 4;
    int ktw = which ? kt + 5 : kt;
    f16x8 v;
#pragma unroll
    for (int j = 0; j < 8; ++j) v[j] = (f16)st[which * 128 + kt * 32 + q * 8 + j];
    *(f16x8*)(Wfrag + WF(ktw, w, nt, q * 16 + l)) = v;
  } else if (m < 36) {  // extras tile ktw=4, q = m-32
    int q = m - 32;
    f16x8 v;
#pragma unroll
    for (int j = 0; j < 8; ++j) {
      int kk = q * 8 + j;
      float x = (kk < 16) ? cellsS[kk] : (kk == 16 ? wio0 : (kk == 17 ? wio1 : 0.f));
      v[j] = (f16)x;
    }
    *(f16x8*)(Wfrag + WF(4, w, nt, q * 16 + l)) = v;
  } else if (m == 36) {
    int col = w * 64 + nt * 16 + l;  // permuted column index
    float base = b_ih[jo] + b_hh[jo];
    biasO[col] = base + dotA + dotS;
    float bp = base + dotA;
    biasP[col] = bp;
    biasPE[col] = bp + wio0 * b_out[0] + wio1 * b_out[1];
  }
}

// ---------------------------------------------------------------------------
// Main: 32 rows/block, 512 threads. Social pooling fused (all loads hoisted,
// packed-bin u64 histogram + shfl butterflies), W_hh/W_eff frags in VGPRs,
// bias enters as MFMA C operand, 1 barrier per step.
// ---------------------------------------------------------------------------
__global__ __launch_bounds__(512, 2) void social_lstm_main(
    const float* __restrict__ obs, const float* __restrict__ nb,
    const f16* __restrict__ Wfrag, const float* __restrict__ biasO,
    const float* __restrict__ biasP, const float* __restrict__ biasPE,
    const float* __restrict__ W_out, const float* __restrict__ b_out,
    float* __restrict__ out) {
  __shared__ __align__(16) f16 Abuf[2 * 4 * 2 * 64 * 8];  // 16 KB
  __shared__ __align__(16) f16 cntA[8 * 2 * 64 * 8];      // 16 KB obs A-panels

  const int tid = threadIdx.x;
  const int w = tid >> 6, ln = tid & 63;
  const int q = ln >> 4, l = ln & 15;
  const int b0 = blockIdx.x * MR;

  // zero Abuf buf0 + all of cntA (channels 18..31 must be 0.0, not garbage)
  for (int i = tid; i < 2048; i += 512) ((uint32_t*)Abuf)[i] = 0u;
  for (int i = tid; i < 4096; i += 512) ((uint32_t*)cntA)[i] = 0u;
  __syncthreads();

  // ---------------- fused social pooling (loads hoisted for MLP) ----------
  {
    const int g = ln >> 4, lg = ln & 15;
    const int r = w * 4 + g;  // local row 0..31
    // hoist ALL neighbor loads: 16 float4 = this lane's 4 tracks
    float4 T[16];
#pragma unroll
    for (int jt = 0; jt < 4; ++jt) {
      const float4* tr =
          (const float4*)(nb + ((size_t)(b0 + r) * 64 + (lg + 16 * jt)) * 16);
#pragma unroll
      for (int u = 0; u < 4; ++u) T[jt * 4 + u] = tr[u];
    }
    const float4* orow = (const float4*)(obs + (size_t)(b0 + r) * 16);
    float4 O0 = orow[0], O1 = orow[1], O2 = orow[2], O3 = orow[3];
    float ox[8] = {O0.x, O0.z, O1.x, O1.z, O2.x, O2.z, O3.x, O3.z};
    float oy[8] = {O0.y, O0.w, O1.y, O1.w, O2.y, O2.w, O3.y, O3.w};
    unsigned long long h[8] = {0ull, 0ull, 0ull, 0ull, 0ull, 0ull, 0ull, 0ull};
#pragma unroll
    for (int jt = 0; jt < 4; ++jt) {
      float nx[8] = {T[jt*4+0].x, T[jt*4+0].z, T[jt*4+1].x, T[jt*4+1].z,
                     T[jt*4+2].x, T[jt*4+2].z, T[jt*4+3].x, T[jt*4+3].z};
      float ny[8] = {T[jt*4+0].y, T[jt*4+0].w, T[jt*4+1].y, T[jt*4+1].w,
                     T[jt*4+2].y, T[jt*4+2].w, T[jt*4+3].y, T[jt*4+3].w};
#pragma unroll
      for (int t = 0; t < 8; ++t) {
        float rx = nx[t] - ox[t], ry = ny[t] - oy[t];
        int ix = (int)floorf(rx + rx);
        int iy = (int)floorf(ry + ry);
        ix = min(max(ix, -2), 1);
        iy = min(max(iy, -2), 1);
        int flat = (ix + 2) * 4 + (iy + 2);   // 0..15, count per lane <= 4
        h[t] += 1ull << (flat * 4);           // 4-bit bins
      }
    }
    auto shx = [](unsigned long long x, int msk) {
      unsigned lo = __shfl_xor((unsigned)x, msk);
      unsigned hi = __shfl_xor((unsigned)(x >> 32), msk);
      return ((unsigned long long)hi << 32) | lo;
    };
#pragma unroll
    for (int t = 0; t < 8; ++t) {
      unsigned long long v = h[t];
      v += shx(v, 1);  // sums <= 8, still fits 4-bit bins
      unsigned long long e0 = v & 0x0F0F0F0F0F0F0F0Full;         // even bins, 8-bit
      unsigned long long e1 = (v >> 4) & 0x0F0F0F0F0F0F0F0Full;  // odd bins
      e0 += shx(e0, 2); e1 += shx(e1, 2);
      e0 += shx(e0, 4); e1 += shx(e1, 4);
      e0 += shx(e0, 8); e1 += shx(e1, 8);
      unsigned long long wsel = (lg & 1) ? e1 : e0;
      unsigned cnt = (unsigned)(wsel >> ((lg >> 1) * 8)) & 0xFFu;
      // channel c = lg -> slot lane (lg>>3)*16 + (r&15), j = lg&7
      cntA[CA(t, r >> 4, (lg >> 3) * 16 + (r & 15), lg & 7)] = (f16)(float)cnt;
    }
    // xy channels 16,17
    int rr = tid >> 4, tt = (tid >> 1) & 7, comp = tid & 1;
    float xv = obs[(size_t)(b0 + rr) * 16 + tt * 2 + comp];
    cntA[CA(tt, rr >> 4, 2 * 16 + (rr & 15), comp)] = (f16)xv;
  }

  // persistent W_hh B fragments + extras
  f16x8 Bh[4][4];
#pragma unroll
  for (int kt = 0; kt < 4; ++kt)
#pragma unroll
    for (int nt = 0; nt < 4; ++nt)
      Bh[kt][nt] = *(const f16x8*)(Wfrag + WF(kt, w, nt, ln));
  f16x8 Bx[4];
#pragma unroll
  for (int nt = 0; nt < 4; ++nt) Bx[nt] = *(const f16x8*)(Wfrag + WF(4, w, nt, ln));

  float creg[8];
#pragma unroll
  for (int i = 0; i < 8; ++i) creg[i] = 0.f;

  // obs-phase bias splats (enter as MFMA C operand of the step's first MFMA)
  f32x4 bOsp[4];
#pragma unroll
  for (int g2 = 0; g2 < 4; ++g2) {
    float v = biasO[w * 64 + g2 * 16 + l];
    bOsp[g2] = (f32x4){v, v, v, v};
  }

  const int hc = w * 16 + l;
  const int aw_kt = hc >> 5, aw_quad = (hc >> 3) & 3, aw_j = l & 7;

  f32x4 acc[2][4];

  auto gemm_h_acc = [&](int rb) {  // chains onto existing acc
#pragma unroll
    for (int kt = 0; kt < 4; ++kt) {
      f16x8 Af[2];
#pragma unroll
      for (int mt = 0; mt < 2; ++mt) Af[mt] = *(const f16x8*)(&Abuf[AB(rb, kt, mt, ln, 0)]);
#pragma unroll
      for (int mt = 0; mt < 2; ++mt)
#pragma unroll
        for (int nt = 0; nt < 4; ++nt)
          acc[mt][nt] =
              __builtin_amdgcn_mfma_f32_16x16x32_f16(Af[mt], Bh[kt][nt], acc[mt][nt], 0, 0, 0);
    }
  };

  auto gemm_h_init = [&](int rb, const f32x4* ci) {  // kt=0 takes C=bias splat
#pragma unroll
    for (int kt = 0; kt < 4; ++kt) {
      f16x8 Af[2];
#pragma unroll
      for (int mt = 0; mt < 2; ++mt) Af[mt] = *(const f16x8*)(&Abuf[AB(rb, kt, mt, ln, 0)]);
#pragma unroll
      for (int mt = 0; mt < 2; ++mt)
#pragma unroll
        for (int nt = 0; nt < 4; ++nt)
          acc[mt][nt] = __builtin_amdgcn_mfma_f32_16x16x32_f16(
              Af[mt], Bh[kt][nt], (kt == 0) ? ci[nt] : acc[mt][nt], 0, 0, 0);
    }
  };

  auto epilogue = [&](int wbuf) {
#pragma unroll
    for (int mt = 0; mt < 2; ++mt) {
#pragma unroll
      for (int reg = 0; reg < 4; ++reg) {
        float p0 = acc[mt][0][reg];
        float p1 = acc[mt][1][reg];
        float p2 = acc[mt][2][reg];
        float p3 = acc[mt][3][reg];
        float iv = fast_sigm(p0), fv = fast_sigm(p1);
        float gv = fast_tanh(p2), ov = fast_sigm(p3);
        int ci = mt * 4 + reg;
        float c2 = fv * creg[ci] + iv * gv;
        creg[ci] = c2;
        float hv = ov * fast_tanh(c2);
        Abuf[AB(wbuf, aw_kt, mt, (q * 4 + reg) + 16 * aw_quad, aw_j)] = (f16)hv;
      }
    }
  };

  // ---------------- observation phase ----------------
#pragma unroll
  for (int t = 0; t < Tobs; ++t) {
    const int rb = t & 1, wb = rb ^ 1;
    __syncthreads();
    f16x8 Ax[2];
#pragma unroll
    for (int mt = 0; mt < 2; ++mt) Ax[mt] = *(const f16x8*)(&cntA[CA(t, mt, ln, 0)]);
#pragma unroll
    for (int mt = 0; mt < 2; ++mt)
#pragma unroll
      for (int nt = 0; nt < 4; ++nt)
        acc[mt][nt] =
            __builtin_amdgcn_mfma_f32_16x16x32_f16(Ax[mt], Bx[nt], bOsp[nt], 0, 0, 0);
    gemm_h_acc(rb);
    epilogue(wb);
  }

  // ---------------- prediction step 0 (prev disp = 0, plain W_hh) ----------
  f32x4 bPsp[4];
#pragma unroll
  for (int g2 = 0; g2 < 4; ++g2) {
    float v = biasP[w * 64 + g2 * 16 + l];
    bPsp[g2] = (f32x4){v, v, v, v};
  }
  {
    const int rb = Tobs & 1, wb = rb ^ 1;  // rb=0, wb=1
    __syncthreads();
    gemm_h_init(rb, bPsp);
    epilogue(wb);
  }

  // swap to W_eff + biasPE; preload W_out dot registers for disp output
#pragma unroll
  for (int kt = 0; kt < 4; ++kt)
#pragma unroll
    for (int nt = 0; nt < 4; ++nt)
      Bh[kt][nt] = *(const f16x8*)(Wfrag + WF(kt + 5, w, nt, ln));
  f32x4 bEsp[4];
#pragma unroll
  for (int g2 = 0; g2 < 4; ++g2) {
    float v = biasPE[w * 64 + g2 * 16 + l];
    bEsp[g2] = (f32x4){v, v, v, v};
  }

  const int d_oi = tid >> 3, d_seg = tid & 7;
  const int d_row = d_oi >> 1, d_jj = d_oi & 1;
  const int d_kt = d_seg >> 1, d_q0 = (d_seg & 1) * 2;
  float wor[16];
  {
    const float4* wp = (const float4*)(W_out + d_jj * 128 + d_seg * 16);
#pragma unroll
    for (int u = 0; u < 4; ++u) {
      float4 v = wp[u];
      wor[4 * u] = v.x; wor[4 * u + 1] = v.y; wor[4 * u + 2] = v.z; wor[4 * u + 3] = v.w;
    }
  }
  const float d_bo = b_out[d_jj];

  auto disp_out = [&](int rbuf, int p) {
    f16x8 hA = *(const f16x8*)(&Abuf[AB(rbuf, d_kt, d_row >> 4, (d_row & 15) + 16 * d_q0, 0)]);
    f16x8 hB = *(const f16x8*)(&Abuf[AB(rbuf, d_kt, d_row >> 4, (d_row & 15) + 16 * (d_q0 + 1), 0)]);
    float s = 0.f;
#pragma unroll
    for (int u = 0; u < 8; ++u) s += wor[u] * (float)hA[u];
#pragma unroll
    for (int u = 0; u < 8; ++u) s += wor[8 + u] * (float)hB[u];
    s += __shfl_xor(s, 1);
    s += __shfl_xor(s, 2);
    s += __shfl_xor(s, 4);
    if ((tid & 7) == 0)
      out[((size_t)(b0 + d_row)) * (PREDL * 2) + p * 2 + d_jj] = s + d_bo;
  };

  // ---------------- prediction steps 1..11 (pure h recurrence) -------------
  for (int p = 1; p < PREDL; ++p) {
    const int s = Tobs + p;
    const int rb = s & 1, wb = rb ^ 1;
    __syncthreads();
    disp_out(rb, p - 1);  // h_{p-1} lives in Abuf[rb]
    gemm_h_init(rb, bEsp);
    epilogue(wb);
  }
  __syncthreads();
  disp_out((Tobs + PREDL) & 1, PREDL - 1);  // h_11 in buf 0
}

// ---------------------------------------------------------------------------
extern "C" void kernel_launch(void* const* d_in, const int* in_sizes, int n_in,
                              void* d_out, int out_size, void* d_ws, size_t ws_size,
                              hipStream_t stream) {
  const float* obs   = (const float*)d_in[0];
  const float* nbrs  = (const float*)d_in[1];
  const float* table = (const float*)d_in[2];
  const float* W_in  = (const float*)d_in[3];
  const float* b_in  = (const float*)d_in[4];
  const float* W_sp  = (const float*)d_in[5];
  const float* b_sp  = (const float*)d_in[6];
  const float* W_ih  = (const float*)d_in[7];
  const float* W_hh  = (const float*)d_in[8];
  const float* b_ih  = (const float*)d_in[9];
  const float* b_hh  = (const float*)d_in[10];
  const float* W_out = (const float*)d_in[11];
  const float* b_out = (const float*)d_in[12];
  float* out = (float*)d_out;

  // ws layout (bytes): Wfrag f16[147456] @0 (294912) | biasO @294912 |
  //                    biasP @296960 | biasPE @299008
  char* ws = (char*)d_ws;
  f16*   Wfrag  = (f16*)(ws);
  float* biasO  = (float*)(ws + 294912);
  float* biasP  = (float*)(ws + 296960);
  float* biasPE = (float*)(ws + 299008);

  pack_all<<<512, 64, 0, stream>>>(W_ih, W_hh, W_in, W_sp, table, b_in, b_sp, b_ih, b_hh,
                                   W_out, b_out, Wfrag, biasO, biasP, biasPE);
  social_lstm_main<<<Bsz / MR, 512, 0, stream>>>(obs, nbrs, Wfrag, biasO, biasP, biasPE,
                                                 W_out, b_out, out);
}